// Round 4
// baseline (298.012 us; speedup 1.0000x reference)
//
#include <hip/hip_runtime.h>
#include <hip/hip_fp16.h>
#include <math.h>

#define D 128
#define GM 64            // rows per GEMM tile
#define CONV_BLOCKS 2048
#define EPB 8192         // edges per scatter block (96 KB LDS)
#define EDGE_WGS 1024    // persistent wgs for binned edge kernel (~4/CU)

typedef _Float16 f16x8 __attribute__((ext_vector_type(8)));
typedef float    f32x4 __attribute__((ext_vector_type(4)));
typedef _Float16 h2_t  __attribute__((ext_vector_type(2)));

__device__ __forceinline__ float dot2acc(unsigned ua, unsigned ub, float c) {
#if __has_builtin(__builtin_amdgcn_fdot2)
  return __builtin_amdgcn_fdot2(__builtin_bit_cast(h2_t, ua),
                                __builtin_bit_cast(h2_t, ub), c, false);
#else
  __half2 a = __builtin_bit_cast(__half2, ua);
  __half2 b = __builtin_bit_cast(__half2, ub);
  float2 fa = __half22float2(a), fb = __half22float2(b);
  return fmaf(fa.x, fb.x, fmaf(fa.y, fb.y, c));
#endif
}

__device__ __forceinline__ unsigned pack2(float x, float y) {
  __half2 h;
  h.x = __float2half_rn(x);
  h.y = __float2half_rn(y);
  return __builtin_bit_cast(unsigned, h);
}

// ---------------- Scatter: LDS counting-sort of 8192-edge windows into 64 bins -
// key = (src-chunk)*8 + (dst-chunk), chunks = 8 equal ranges of [0,N).
// NO global atomics; each block writes only its own fixed window -> graph-replay
// idempotent (round-2 failure mode eliminated). runs[b*64+k] = {start, len}.
__global__ __launch_bounds__(256) void scatter_kernel(
    const int* __restrict__ eidx, int E, int N,
    int2* __restrict__ sSD, int* __restrict__ sE,
    int2* __restrict__ runs)
{
  __shared__ int2 sd[EPB];          // 64 KB
  __shared__ int  se[EPB];          // 32 KB
  __shared__ int  hist[64];
  __shared__ int  base[64];
  __shared__ int  cur[64];

  const int tid = threadIdx.x;
  const int b   = blockIdx.x;
  const int e0  = b * EPB;
  const int cnt = min(EPB, E - e0);
  const float scale = 8.0f / (float)N;

  for (int i = tid; i < 64; i += 256) hist[i] = 0;
  __syncthreads();

  // pass 1: histogram (keys cached in regs; s,d re-read in pass 2 from L2)
  int myk[EPB / 256];
  #pragma unroll
  for (int j = 0; j < EPB / 256; j++) {
    int i = tid + j * 256;
    if (i < cnt) {
      int s = eidx[e0 + i];
      int d = eidx[E + e0 + i];
      int bs = min(7, (int)((float)s * scale));
      int bd = min(7, (int)((float)d * scale));
      int k = bs * 8 + bd;
      myk[j] = k;
      atomicAdd(&hist[k], 1);
    } else myk[j] = -1;
  }
  __syncthreads();

  if (tid == 0) {
    int acc = 0;
    for (int k = 0; k < 64; k++) { base[k] = acc; cur[k] = acc; acc += hist[k]; }
  }
  __syncthreads();

  // pass 2: rank via LDS cursor, place into LDS
  #pragma unroll
  for (int j = 0; j < EPB / 256; j++) {
    int i = tid + j * 256;
    if (myk[j] >= 0) {
      int s = eidx[e0 + i];
      int d = eidx[E + e0 + i];
      int pos = atomicAdd(&cur[myk[j]], 1);
      sd[pos] = make_int2(s, d);
      se[pos] = e0 + i;
    }
  }
  __syncthreads();

  // stream LDS -> global (coalesced), plus runs table
  for (int i = tid; i < cnt; i += 256) {
    sSD[e0 + i] = sd[i];
    sE[e0 + i]  = se[i];
  }
  for (int k = tid; k < 64; k += 256)
    runs[b * 64 + k] = make_int2(e0 + base[k], hist[k]);
}

// ---------------- Fused prep kernel (r3-verified, unchanged) ------------------
__global__ __launch_bounds__(256) void prep3_kernel(
    const float* __restrict__ Xout, const float* __restrict__ Xin,
    const float* __restrict__ W, __half* __restrict__ Yh,
    __half* __restrict__ Xh, int N, int gemm_blocks)
{
  __shared__ __align__(16) __half sA[GM * D];     // 16 KB; reused as sC
  __shared__ __align__(16) __half sB[D * D];      // 32 KB

  const int tid = threadIdx.x;
  const int bid = blockIdx.x;

  if (bid >= gemm_blocks) {
    const int cb = bid - gemm_blocks;
    const int n4 = N * (D / 4);
    const int stride = CONV_BLOCKS * 256 * 4;
    for (int base = (cb * 256 + tid) * 4; base < n4; base += stride) {
      float4 v[4];
      #pragma unroll
      for (int j = 0; j < 4; j++)
        if (base + j < n4) v[j] = ((const float4*)Xin)[base + j];
      #pragma unroll
      for (int j = 0; j < 4; j++)
        if (base + j < n4) {
          uint2 u;
          u.x = pack2(v[j].x, v[j].y);
          u.y = pack2(v[j].z, v[j].w);
          ((uint2*)Xh)[base + j] = u;
        }
    }
    return;
  }

  const int row0 = bid * GM;

  float4 v[8];
  #pragma unroll
  for (int i = 0; i < 4; i++) {
    int gi = tid + i * 256;
    int r = gi >> 4, q = gi & 15;
    int gr = row0 + r;
    if (gr < N) {
      const float4* s = (const float4*)(Xout + (size_t)gr * D + q * 8);
      v[2*i]   = s[0];
      v[2*i+1] = s[1];
    } else {
      v[2*i]   = make_float4(0.f, 0.f, 0.f, 0.f);
      v[2*i+1] = make_float4(0.f, 0.f, 0.f, 0.f);
    }
  }
  #pragma unroll
  for (int i = 0; i < 4; i++) {
    int gi = tid + i * 256;
    int r = gi >> 4, q = gi & 15;
    uint4 u;
    u.x = pack2(v[2*i].x,   v[2*i].y);
    u.y = pack2(v[2*i].z,   v[2*i].w);
    u.z = pack2(v[2*i+1].x, v[2*i+1].y);
    u.w = pack2(v[2*i+1].z, v[2*i+1].w);
    *(uint4*)(sA + r * D + ((q ^ (r & 7)) << 3)) = u;
  }

  #pragma unroll
  for (int i = 0; i < 64; i++) {
    int o = tid + i * 256;
    int k = o >> 7;
    int n = o & 127;
    __half h = __float2half_rn(W[o]);
    int gk = k >> 3;
    sB[n * 128 + (((gk + n) & 15) << 3) + (k & 7)] = h;
  }
  __syncthreads();

  const int lane = tid & 63, wave = tid >> 6;
  const int m = lane & 15, quad = lane >> 4;
  const int rloc = wave * 16 + m;

  f32x4 acc[8];
  #pragma unroll
  for (int ct = 0; ct < 8; ct++) acc[ct] = (f32x4){0.f, 0.f, 0.f, 0.f};

  #pragma unroll
  for (int ks = 0; ks < 4; ks++) {
    const int g = ks * 4 + quad;
    f16x8 bfrag[8];
    #pragma unroll
    for (int ct = 0; ct < 8; ct++) {
      int n = ct * 16 + m;
      bfrag[ct] = *(const f16x8*)(sB + n * 128 + (((g + n) & 15) << 3));
    }
    f16x8 afrag = *(const f16x8*)(sA + rloc * D + ((g ^ (rloc & 7)) << 3));
    #pragma unroll
    for (int ct = 0; ct < 8; ct++)
      acc[ct] = __builtin_amdgcn_mfma_f32_16x16x32_f16(
          afrag, bfrag[ct], acc[ct], 0, 0, 0);
  }

  __syncthreads();
  __half* sC = sA;
  #pragma unroll
  for (int ct = 0; ct < 8; ct++)
    #pragma unroll
    for (int reg = 0; reg < 4; reg++) {
      int r = wave * 16 + quad * 4 + reg;
      sC[r * D + ct * 16 + m] = __float2half_rn(acc[ct][reg]);
    }
  __syncthreads();
  #pragma unroll
  for (int i = 0; i < 4; i++) {
    int gi = tid + i * 256;
    int r = gi >> 4, q = gi & 15;
    int gr = row0 + r;
    if (gr < N)
      *(uint4*)(Yh + (size_t)gr * D + q * 8) = *(const uint4*)(sC + r * D + q * 8);
  }
}

// ---------------- Binned edge kernel: persistent wgs, bin-major pair order -----
// Pair p = bin*NB + b. At ~1024 concurrent wgs, active pairs span ~5 bins
// (~32 MB working set ~= aggregate L2) -> both endpoint chunks L2-resident.
__global__ __launch_bounds__(256) void edge_binned_kernel(
    const __half* __restrict__ Yh, const __half* __restrict__ Xh,
    const int2* __restrict__ sSD, const int* __restrict__ sE,
    const int2* __restrict__ runs, float* __restrict__ out, int NB)
{
  const int NP = NB * 64;
  const int grp = threadIdx.x >> 4;
  const int l   = threadIdx.x & 15;

  for (int p = blockIdx.x; p < NP; p += gridDim.x) {
    int bin = p / NB;
    int b   = p - bin * NB;
    int2 run = runs[b * 64 + bin];
    int start = run.x, len = run.y;

    for (int off = grp * 2; off < len; off += 32) {
      int i0 = start + off;
      bool has1 = (off + 1 < len);
      int2 sd0 = sSD[i0];
      int2 sd1 = has1 ? sSD[i0 + 1] : sd0;

      uint4 a0 = ((const uint4*)(Yh + (size_t)sd0.x * D))[l];
      uint4 b0 = ((const uint4*)(Xh + (size_t)sd0.y * D))[l];
      uint4 a1 = ((const uint4*)(Yh + (size_t)sd1.x * D))[l];
      uint4 b1 = ((const uint4*)(Xh + (size_t)sd1.y * D))[l];

      float pv = 0.f, qv = 0.f;
      pv = dot2acc(a0.x, b0.x, pv);  qv = dot2acc(a1.x, b1.x, qv);
      pv = dot2acc(a0.y, b0.y, pv);  qv = dot2acc(a1.y, b1.y, qv);
      pv = dot2acc(a0.z, b0.z, pv);  qv = dot2acc(a1.z, b1.z, qv);
      pv = dot2acc(a0.w, b0.w, pv);  qv = dot2acc(a1.w, b1.w, qv);

      pv += __shfl_xor(pv, 8);  qv += __shfl_xor(qv, 8);
      pv += __shfl_xor(pv, 4);  qv += __shfl_xor(qv, 4);
      pv += __shfl_xor(pv, 2);  qv += __shfl_xor(qv, 2);
      pv += __shfl_xor(pv, 1);  qv += __shfl_xor(qv, 1);

      if (l == 0) {
        out[sE[i0]] = 1.0f / (1.0f + __expf(-pv));
        if (has1) out[sE[i0 + 1]] = 1.0f / (1.0f + __expf(-qv));
      }
    }
  }
}

// ---------------- r3 edge kernel (fallback if ws lacks sort room) -------------
__global__ __launch_bounds__(256) void edge_dot2_kernel(
    const __half* __restrict__ Yh, const __half* __restrict__ Xh,
    const int* __restrict__ idx, float* __restrict__ out, int E)
{
  long long gid = (long long)blockIdx.x * 256 + threadIdx.x;
  int slot = (int)(gid >> 4);
  int l    = (int)(gid & 15);
  int e0 = slot * 2;
  if (e0 >= E) return;
  int e1 = e0 + 1;
  bool has1 = (e1 < E);

  int s0 = idx[e0];
  int d0 = idx[E + e0];
  int s1 = has1 ? idx[e1] : s0;
  int d1 = has1 ? idx[E + e1] : d0;

  uint4 a0 = ((const uint4*)(Yh + (size_t)s0 * D))[l];
  uint4 b0 = ((const uint4*)(Xh + (size_t)d0 * D))[l];
  uint4 a1 = ((const uint4*)(Yh + (size_t)s1 * D))[l];
  uint4 b1 = ((const uint4*)(Xh + (size_t)d1 * D))[l];

  float p = 0.f, q = 0.f;
  p = dot2acc(a0.x, b0.x, p);  q = dot2acc(a1.x, b1.x, q);
  p = dot2acc(a0.y, b0.y, p);  q = dot2acc(a1.y, b1.y, q);
  p = dot2acc(a0.z, b0.z, p);  q = dot2acc(a1.z, b1.z, q);
  p = dot2acc(a0.w, b0.w, p);  q = dot2acc(a1.w, b1.w, q);

  p += __shfl_xor(p, 8);  q += __shfl_xor(q, 8);
  p += __shfl_xor(p, 4);  q += __shfl_xor(q, 4);
  p += __shfl_xor(p, 2);  q += __shfl_xor(q, 2);
  p += __shfl_xor(p, 1);  q += __shfl_xor(q, 1);

  if (l == 0) {
    float2 o;
    o.x = 1.0f / (1.0f + __expf(-p));
    o.y = 1.0f / (1.0f + __expf(-q));
    if (has1) *(float2*)(out + e0) = o;
    else      out[e0] = o.x;
  }
}

// ---------------- Fallback: direct bilinear per edge (only if ws tiny) --------
__global__ __launch_bounds__(256) void edge_bilinear_direct_kernel(
    const float* __restrict__ Xout, const float* __restrict__ Xin,
    const float* __restrict__ W, const int* __restrict__ idx,
    float* __restrict__ out, int E)
{
  long long gid = (long long)blockIdx.x * 256 + threadIdx.x;
  int e = (int)(gid >> 6);
  if (e >= E) return;
  int l = (int)(gid & 63);

  int src = idx[e];
  int dst = idx[E + e];
  const float* a = Xout + (size_t)src * D;
  const float* b = Xin  + (size_t)dst * D;

  float s = 0.f;
  #pragma unroll
  for (int kk = 0; kk < 2; kk++) {
    int k = l + kk * 64;
    float ak = a[k];
    float t = 0.f;
    #pragma unroll 8
    for (int j = 0; j < D; j++) t = fmaf(W[(size_t)k * D + j], b[j], t);
    s = fmaf(ak, t, s);
  }
  #pragma unroll
  for (int off = 32; off >= 1; off >>= 1) s += __shfl_xor(s, off);
  if (l == 0) out[e] = 1.0f / (1.0f + __expf(-s));
}

extern "C" void kernel_launch(void* const* d_in, const int* in_sizes, int n_in,
                              void* d_out, int out_size, void* d_ws, size_t ws_size,
                              hipStream_t stream) {
  const float* x_in  = (const float*)d_in[0];   // [N, 128]
  const float* x_out = (const float*)d_in[1];   // [N, 128]
  const int*   eidx  = (const int*)d_in[2];     // [2, E]
  const float* W     = (const float*)d_in[3];   // [128,128]
  float* out = (float*)d_out;

  const int N = in_sizes[0] / D;
  const int E = in_sizes[2] / 2;

  const size_t half_rows = (size_t)N * D * sizeof(__half);  // 25.6 MB each
  const int NB = (E + EPB - 1) / EPB;

  size_t off_yh  = 0;
  size_t off_xh  = off_yh + half_rows;
  size_t off_sd  = off_xh + half_rows;
  size_t off_se  = off_sd + (size_t)E * sizeof(int2);
  size_t off_rn  = off_se + (size_t)E * sizeof(int);
  size_t total_ws = off_rn + (size_t)NB * 64 * sizeof(int2);

  if (ws_size >= total_ws) {
    __half* Yh   = (__half*)((char*)d_ws + off_yh);
    __half* Xh   = (__half*)((char*)d_ws + off_xh);
    int2*   sSD  = (int2*)((char*)d_ws + off_sd);
    int*    sE   = (int*)((char*)d_ws + off_se);
    int2*   runs = (int2*)((char*)d_ws + off_rn);

    scatter_kernel<<<dim3(NB), 256, 0, stream>>>(eidx, E, N, sSD, sE, runs);

    int gemm_blocks = (N + GM - 1) / GM;
    dim3 g1(gemm_blocks + CONV_BLOCKS);
    prep3_kernel<<<g1, 256, 0, stream>>>(x_out, x_in, W, Yh, Xh, N, gemm_blocks);

    edge_binned_kernel<<<dim3(EDGE_WGS), 256, 0, stream>>>(Yh, Xh, sSD, sE,
                                                           runs, out, NB);
  } else if (ws_size >= 2 * half_rows) {
    __half* Yh = (__half*)d_ws;
    __half* Xh = (__half*)((char*)d_ws + half_rows);

    int gemm_blocks = (N + GM - 1) / GM;
    dim3 g1(gemm_blocks + CONV_BLOCKS);
    prep3_kernel<<<g1, 256, 0, stream>>>(x_out, x_in, W, Yh, Xh, N, gemm_blocks);

    long long slots = ((long long)E + 1) / 2;
    long long total = slots * 16;
    dim3 g2((unsigned)((total + 255) / 256));
    edge_dot2_kernel<<<g2, 256, 0, stream>>>(Yh, Xh, eidx, out, E);
  } else {
    long long total = (long long)E * 64;
    dim3 g((unsigned)((total + 255) / 256));
    edge_bilinear_direct_kernel<<<g, 256, 0, stream>>>(x_out, x_in, W, eidx, out, E);
  }
}

// Round 5
// 241.785 us; speedup vs baseline: 1.2326x; 1.2326x over previous
//
#include <hip/hip_runtime.h>
#include <hip/hip_fp16.h>
#include <math.h>

#define D 128
#define GM 64            // rows per GEMM tile
#define GEMM_WGS 512     // persistent GEMM workgroups (sB staged once each)
#define CONV_BLOCKS 2048

typedef _Float16 f16x8 __attribute__((ext_vector_type(8)));
typedef float    f32x4 __attribute__((ext_vector_type(4)));
typedef _Float16 h2_t  __attribute__((ext_vector_type(2)));

__device__ __forceinline__ float dot2acc(unsigned ua, unsigned ub, float c) {
#if __has_builtin(__builtin_amdgcn_fdot2)
  return __builtin_amdgcn_fdot2(__builtin_bit_cast(h2_t, ua),
                                __builtin_bit_cast(h2_t, ub), c, false);
#else
  __half2 a = __builtin_bit_cast(__half2, ua);
  __half2 b = __builtin_bit_cast(__half2, ub);
  float2 fa = __half22float2(a), fb = __half22float2(b);
  return fmaf(fa.x, fb.x, fmaf(fa.y, fb.y, c));
#endif
}

__device__ __forceinline__ unsigned pack2(float x, float y) {
  __half2 h;
  h.x = __float2half_rn(x);
  h.y = __float2half_rn(y);
  return __builtin_bit_cast(unsigned, h);
}

// ---------------- Fused prep kernel v4: persistent GEMM wgs -------------------
// wgs [0, GEMM_WGS): stage W->sB ONCE (r0-verified transpose+swizzle), then
//   grid-stride over 64-row tiles of Y = Xout @ W (r3-verified tile body).
// wgs [GEMM_WGS, +CONV_BLOCKS): grid-stride x_in fp32->fp16 convert (r3-verbatim).
__global__ __launch_bounds__(256) void prep4_kernel(
    const float* __restrict__ Xout, const float* __restrict__ Xin,
    const float* __restrict__ W, __half* __restrict__ Yh,
    __half* __restrict__ Xh, int N, int gemm_tiles)
{
  __shared__ __align__(16) __half sA[GM * D];     // 16 KB; reused as sC
  __shared__ __align__(16) __half sB[D * D];      // 32 KB, staged once per wg

  const int tid = threadIdx.x;
  const int bid = blockIdx.x;

  if (bid >= GEMM_WGS) {
    // ---- convert role: Xh = (half)Xin ----
    const int cb = bid - GEMM_WGS;
    const int n4 = N * (D / 4);
    const int stride = CONV_BLOCKS * 256 * 4;
    for (int base = (cb * 256 + tid) * 4; base < n4; base += stride) {
      float4 v[4];
      #pragma unroll
      for (int j = 0; j < 4; j++)
        if (base + j < n4) v[j] = ((const float4*)Xin)[base + j];
      #pragma unroll
      for (int j = 0; j < 4; j++)
        if (base + j < n4) {
          uint2 u;
          u.x = pack2(v[j].x, v[j].y);
          u.y = pack2(v[j].z, v[j].w);
          ((uint2*)Xh)[base + j] = u;
        }
    }
    return;
  }

  // ---- GEMM role ----
  // Stage B once: transpose W (fp32 k-major) -> fp16 n-major swizzled LDS.
  #pragma unroll
  for (int i = 0; i < 64; i++) {
    int o = tid + i * 256;             // 0..16383
    int k = o >> 7;
    int n = o & 127;
    __half h = __float2half_rn(W[o]);
    int gk = k >> 3;
    sB[n * 128 + (((gk + n) & 15) << 3) + (k & 7)] = h;
  }
  // (visibility of sB covered by the per-tile __syncthreads below)

  const int lane = tid & 63, wave = tid >> 6;
  const int m = lane & 15, quad = lane >> 4;
  const int rloc = wave * 16 + m;

  for (int t = bid; t < gemm_tiles; t += GEMM_WGS) {
    const int row0 = t * GM;

    // Stage A: 1024 granules (16B fp16 = 32B fp32 src), 4 per thread.
    float4 v[8];
    #pragma unroll
    for (int i = 0; i < 4; i++) {
      int gi = tid + i * 256;          // granule id 0..1023
      int r = gi >> 4, q = gi & 15;
      int gr = row0 + r;
      if (gr < N) {
        const float4* s = (const float4*)(Xout + (size_t)gr * D + q * 8);
        v[2*i]   = s[0];
        v[2*i+1] = s[1];
      } else {
        v[2*i]   = make_float4(0.f, 0.f, 0.f, 0.f);
        v[2*i+1] = make_float4(0.f, 0.f, 0.f, 0.f);
      }
    }
    #pragma unroll
    for (int i = 0; i < 4; i++) {
      int gi = tid + i * 256;
      int r = gi >> 4, q = gi & 15;
      uint4 u;
      u.x = pack2(v[2*i].x,   v[2*i].y);
      u.y = pack2(v[2*i].z,   v[2*i].w);
      u.z = pack2(v[2*i+1].x, v[2*i+1].y);
      u.w = pack2(v[2*i+1].z, v[2*i+1].w);
      *(uint4*)(sA + r * D + ((q ^ (r & 7)) << 3)) = u;   // XOR swizzle (r1-verified)
    }
    __syncthreads();                   // sA (and first-iter sB) visible

    f32x4 acc[8];
    #pragma unroll
    for (int ct = 0; ct < 8; ct++) acc[ct] = (f32x4){0.f, 0.f, 0.f, 0.f};

    #pragma unroll
    for (int ks = 0; ks < 4; ks++) {
      const int g = ks * 4 + quad;     // k-granule: k = g*8 + j
      f16x8 bfrag[8];
      #pragma unroll
      for (int ct = 0; ct < 8; ct++) {
        int n = ct * 16 + m;
        bfrag[ct] = *(const f16x8*)(sB + n * 128 + (((g + n) & 15) << 3));
      }
      f16x8 afrag = *(const f16x8*)(sA + rloc * D + ((g ^ (rloc & 7)) << 3));
      #pragma unroll
      for (int ct = 0; ct < 8; ct++)
        acc[ct] = __builtin_amdgcn_mfma_f32_16x16x32_f16(
            afrag, bfrag[ct], acc[ct], 0, 0, 0);
    }

    // Epilogue: acc -> sC (reuse sA) -> coalesced uint4 stores.
    __syncthreads();                   // afrag reads done before sC overwrite
    __half* sC = sA;
    #pragma unroll
    for (int ct = 0; ct < 8; ct++)
      #pragma unroll
      for (int reg = 0; reg < 4; reg++) {
        int r = wave * 16 + quad * 4 + reg;
        sC[r * D + ct * 16 + m] = __float2half_rn(acc[ct][reg]);
      }
    __syncthreads();                   // sC visible for stores
    #pragma unroll
    for (int i = 0; i < 4; i++) {
      int gi = tid + i * 256;          // 0..1023 granules
      int r = gi >> 4, q = gi & 15;
      int gr = row0 + r;
      if (gr < N)
        *(uint4*)(Yh + (size_t)gr * D + q * 8) = *(const uint4*)(sC + r * D + q * 8);
    }
    __syncthreads();                   // stores read sC before next-iter sA writes
  }
}

// ---------------- Edge kernel: out[e] = sigmoid(Yh[src] . Xh[dst]), 2 edges/thread
// (r0/r3 best-measured variant, verbatim)
__global__ __launch_bounds__(256) void edge_dot2_kernel(
    const __half* __restrict__ Yh, const __half* __restrict__ Xh,
    const int* __restrict__ idx, float* __restrict__ out, int E)
{
  long long gid = (long long)blockIdx.x * 256 + threadIdx.x;
  int slot = (int)(gid >> 4);
  int l    = (int)(gid & 15);
  int e0 = slot * 2;
  if (e0 >= E) return;
  int e1 = e0 + 1;
  bool has1 = (e1 < E);

  int s0 = idx[e0];
  int d0 = idx[E + e0];
  int s1 = has1 ? idx[e1] : s0;
  int d1 = has1 ? idx[E + e1] : d0;

  uint4 a0 = ((const uint4*)(Yh + (size_t)s0 * D))[l];
  uint4 b0 = ((const uint4*)(Xh + (size_t)d0 * D))[l];
  uint4 a1 = ((const uint4*)(Yh + (size_t)s1 * D))[l];
  uint4 b1 = ((const uint4*)(Xh + (size_t)d1 * D))[l];

  float p = 0.f, q = 0.f;
  p = dot2acc(a0.x, b0.x, p);  q = dot2acc(a1.x, b1.x, q);
  p = dot2acc(a0.y, b0.y, p);  q = dot2acc(a1.y, b1.y, q);
  p = dot2acc(a0.z, b0.z, p);  q = dot2acc(a1.z, b1.z, q);
  p = dot2acc(a0.w, b0.w, p);  q = dot2acc(a1.w, b1.w, q);

  p += __shfl_xor(p, 8);  q += __shfl_xor(q, 8);
  p += __shfl_xor(p, 4);  q += __shfl_xor(q, 4);
  p += __shfl_xor(p, 2);  q += __shfl_xor(q, 2);
  p += __shfl_xor(p, 1);  q += __shfl_xor(q, 1);

  if (l == 0) {
    float2 o;
    o.x = 1.0f / (1.0f + __expf(-p));
    o.y = 1.0f / (1.0f + __expf(-q));
    if (has1) *(float2*)(out + e0) = o;
    else      out[e0] = o.x;
  }
}

// ---------------- Fallback: direct bilinear per edge (only if ws too small) ----
__global__ __launch_bounds__(256) void edge_bilinear_direct_kernel(
    const float* __restrict__ Xout, const float* __restrict__ Xin,
    const float* __restrict__ W, const int* __restrict__ idx,
    float* __restrict__ out, int E)
{
  long long gid = (long long)blockIdx.x * 256 + threadIdx.x;
  int e = (int)(gid >> 6);
  if (e >= E) return;
  int l = (int)(gid & 63);

  int src = idx[e];
  int dst = idx[E + e];
  const float* a = Xout + (size_t)src * D;
  const float* b = Xin  + (size_t)dst * D;

  float s = 0.f;
  #pragma unroll
  for (int kk = 0; kk < 2; kk++) {
    int k = l + kk * 64;
    float ak = a[k];
    float t = 0.f;
    #pragma unroll 8
    for (int j = 0; j < D; j++) t = fmaf(W[(size_t)k * D + j], b[j], t);
    s = fmaf(ak, t, s);
  }
  #pragma unroll
  for (int off = 32; off >= 1; off >>= 1) s += __shfl_xor(s, off);
  if (l == 0) out[e] = 1.0f / (1.0f + __expf(-s));
}

extern "C" void kernel_launch(void* const* d_in, const int* in_sizes, int n_in,
                              void* d_out, int out_size, void* d_ws, size_t ws_size,
                              hipStream_t stream) {
  const float* x_in  = (const float*)d_in[0];   // [N, 128]
  const float* x_out = (const float*)d_in[1];   // [N, 128]
  const int*   eidx  = (const int*)d_in[2];     // [2, E]
  const float* W     = (const float*)d_in[3];   // [128,128]
  float* out = (float*)d_out;

  const int N = in_sizes[0] / D;
  const int E = in_sizes[2] / 2;

  const size_t half_rows = (size_t)N * D * sizeof(__half);  // 25.6 MB each

  if (ws_size >= 2 * half_rows) {
    __half* Yh = (__half*)d_ws;
    __half* Xh = (__half*)((char*)d_ws + half_rows);

    int gemm_tiles = (N + GM - 1) / GM;
    dim3 g1(GEMM_WGS + CONV_BLOCKS);
    prep4_kernel<<<g1, 256, 0, stream>>>(x_out, x_in, W, Yh, Xh, N, gemm_tiles);

    long long slots = ((long long)E + 1) / 2;
    long long total = slots * 16;
    dim3 g2((unsigned)((total + 255) / 256));
    edge_dot2_kernel<<<g2, 256, 0, stream>>>(Yh, Xh, eidx, out, E);
  } else {
    long long total = (long long)E * 64;
    dim3 g((unsigned)((total + 255) / 256));
    edge_bilinear_direct_kernel<<<g, 256, 0, stream>>>(x_out, x_in, W, eidx, out, E);
  }
}